// Round 1
// baseline (21016.347 us; speedup 1.0000x reference)
//
#include <hip/hip_runtime.h>

// Problem constants (S=max_seq_len, B=batch, H=hidden)
#define SS 512
#define BB 256
#define HH 512

typedef __bf16 bf16x8 __attribute__((ext_vector_type(8)));
typedef float f32x4 __attribute__((ext_vector_type(4)));

// fp32 -> bf16 round-to-nearest-even (bit trick)
static __device__ __forceinline__ unsigned short f2bf(float f) {
  unsigned int u = __float_as_uint(f);
  u += 0x7fffu + ((u >> 16) & 1u);
  return (unsigned short)(u >> 16);
}

#define BM 64
#define BN 64
#define BK 32
#define LDP 56   // LDS row pitch (elems): 112B -> 16B-aligned b128 reads, 2-way banks (free)

// C[M,N] = A[M,K] @ B^T (+bias), A split at ksplit between A0/A1 (concat trick).
// transB=0: B is [N][K] k-contig (NT). transB=1: B is [K][N] n-contig (NN, staged transposed).
// Per-z offsets Az/Bz/Cz (elements) for batched (per-b) use.
__global__ __launch_bounds__(256) void gemm_bf16(
    const float* __restrict__ A0, const float* __restrict__ A1,
    const float* __restrict__ Bm, const float* __restrict__ bias,
    float* __restrict__ C,
    int K, int ksplit,
    long lda0, long lda1, long ldb, long ldc,
    long Az, long Bz, long Cz, int transB)
{
  __shared__ unsigned short As[BM][LDP];
  __shared__ unsigned short Bs[BN][LDP];

  const int tid = threadIdx.x;
  const int wave = tid >> 6, lane = tid & 63;
  const long m0 = (long)blockIdx.y * BM;
  const int n0 = blockIdx.x * BN;
  A0 += (long)blockIdx.z * Az;
  A1 += (long)blockIdx.z * Az;
  Bm += (long)blockIdx.z * Bz;
  C  += (long)blockIdx.z * Cz;

  const int wm = (wave & 1) * 32;   // wave sub-tile: 32x32
  const int wn = (wave >> 1) * 32;

  f32x4 acc[2][2];
#pragma unroll
  for (int i = 0; i < 2; i++)
#pragma unroll
    for (int j = 0; j < 2; j++) acc[i][j] = (f32x4){0.f, 0.f, 0.f, 0.f};

  for (int kk = 0; kk < K; kk += BK) {
    // ---- stage A tile: 64 rows x 32 k (fp32 -> bf16) ----
#pragma unroll
    for (int i = 0; i < 2; i++) {
      int slot = tid * 2 + i;          // 0..511 float4 slots
      int row = slot >> 3, c4 = slot & 7;
      int kg = kk + c4 * 4;
      const float* src = (kg < ksplit) ? (A0 + (m0 + row) * lda0 + kg)
                                       : (A1 + (m0 + row) * lda1 + (kg - ksplit));
      float4 v = *(const float4*)src;
      *(ushort4*)&As[row][c4 * 4] =
          make_ushort4(f2bf(v.x), f2bf(v.y), f2bf(v.z), f2bf(v.w));
    }
    // ---- stage B tile ----
    if (!transB) {
#pragma unroll
      for (int i = 0; i < 2; i++) {
        int slot = tid * 2 + i;
        int row = slot >> 3, c4 = slot & 7;
        int kg = kk + c4 * 4;
        float4 v = *(const float4*)(Bm + (long)(n0 + row) * ldb + kg);
        *(ushort4*)&Bs[row][c4 * 4] =
            make_ushort4(f2bf(v.x), f2bf(v.y), f2bf(v.z), f2bf(v.w));
      }
    } else {
      // B global is [K][N]; transpose into Bs[n][k] during staging
#pragma unroll
      for (int i = 0; i < 2; i++) {
        int slot = tid * 2 + i;        // k = slot>>4 (0..31), n4 = slot&15
        int krow = slot >> 4, n4 = slot & 15;
        float4 v = *(const float4*)(Bm + (long)(kk + krow) * ldb + n0 + n4 * 4);
        Bs[n4 * 4 + 0][krow] = f2bf(v.x);
        Bs[n4 * 4 + 1][krow] = f2bf(v.y);
        Bs[n4 * 4 + 2][krow] = f2bf(v.z);
        Bs[n4 * 4 + 3][krow] = f2bf(v.w);
      }
    }
    __syncthreads();

    const int kf = (lane >> 4) * 8;   // A/B operand: elem = row l&15, k = (l>>4)*8+j
    const int rl = lane & 15;
    bf16x8 a0 = *(const bf16x8*)&As[wm + rl][kf];
    bf16x8 a1 = *(const bf16x8*)&As[wm + 16 + rl][kf];
    bf16x8 b0 = *(const bf16x8*)&Bs[wn + rl][kf];
    bf16x8 b1 = *(const bf16x8*)&Bs[wn + 16 + rl][kf];
    acc[0][0] = __builtin_amdgcn_mfma_f32_16x16x32_bf16(a0, b0, acc[0][0], 0, 0, 0);
    acc[0][1] = __builtin_amdgcn_mfma_f32_16x16x32_bf16(a0, b1, acc[0][1], 0, 0, 0);
    acc[1][0] = __builtin_amdgcn_mfma_f32_16x16x32_bf16(a1, b0, acc[1][0], 0, 0, 0);
    acc[1][1] = __builtin_amdgcn_mfma_f32_16x16x32_bf16(a1, b1, acc[1][1], 0, 0, 0);
    __syncthreads();
  }

  // ---- epilogue: C/D layout col=lane&15, row=(lane>>4)*4+reg (m89-verified) ----
  const int rq = (lane >> 4) * 4;
  const int cl = lane & 15;
#pragma unroll
  for (int mt = 0; mt < 2; mt++)
#pragma unroll
    for (int nt = 0; nt < 2; nt++) {
      int col = n0 + wn + nt * 16 + cl;
      float bv = bias ? bias[col] : 0.f;
      long rbase = m0 + wm + mt * 16 + rq;
#pragma unroll
      for (int r = 0; r < 4; r++)
        C[(rbase + r) * ldc + col] = acc[mt][nt][r] + bv;
    }
}

// Row-wise softmax over 512 cols; one wave per row.
__global__ __launch_bounds__(256) void softmax512(float* __restrict__ P) {
  long row = (long)blockIdx.x * 4 + (threadIdx.x >> 6);
  int lane = threadIdx.x & 63;
  float* p = P + row * 512;
  float4 v0 = ((float4*)p)[lane];
  float4 v1 = ((float4*)p)[lane + 64];
  float m = fmaxf(fmaxf(fmaxf(v0.x, v0.y), fmaxf(v0.z, v0.w)),
                  fmaxf(fmaxf(v1.x, v1.y), fmaxf(v1.z, v1.w)));
#pragma unroll
  for (int o = 32; o > 0; o >>= 1) m = fmaxf(m, __shfl_xor(m, o));
  v0.x = __expf(v0.x - m); v0.y = __expf(v0.y - m);
  v0.z = __expf(v0.z - m); v0.w = __expf(v0.w - m);
  v1.x = __expf(v1.x - m); v1.y = __expf(v1.y - m);
  v1.z = __expf(v1.z - m); v1.w = __expf(v1.w - m);
  float s = v0.x + v0.y + v0.z + v0.w + v1.x + v1.y + v1.z + v1.w;
#pragma unroll
  for (int o = 32; o > 0; o >>= 1) s += __shfl_xor(s, o);
  float inv = 1.f / s;
  v0.x *= inv; v0.y *= inv; v0.z *= inv; v0.w *= inv;
  v1.x *= inv; v1.y *= inv; v1.z *= inv; v1.w *= inv;
  ((float4*)p)[lane] = v0;
  ((float4*)p)[lane + 64] = v1;
}

// W_cat[2048][1024] bf16 = concat_k(W_ih, W_hh); converted once, reused by all 512 steps.
__global__ __launch_bounds__(256) void prep_wcat(const float* __restrict__ Wih,
                                                 const float* __restrict__ Whh,
                                                 unsigned short* __restrict__ out) {
  long idx = (long)blockIdx.x * 256 + threadIdx.x;   // 2048*1024 elems
  int n = (int)(idx >> 10), k = (int)(idx & 1023);
  float v = (k < 512) ? Wih[(long)n * 512 + k] : Whh[(long)n * 512 + (k - 512)];
  out[idx] = f2bf(v);
}

// One LSTM timestep: G = [x_t | h_prev] @ W_cat^T, fused i/f/g/o cell update.
// grid (16,4): block = 64 batch rows x (32 cols x 4 gates). wave g owns gate g.
__global__ __launch_bounds__(256) void lstm_step(
    const float* __restrict__ xt,            // h + t*B*H  [B][H] fp32
    const float* __restrict__ hprev,         // [B][H] fp32
    const unsigned short* __restrict__ Wcat, // [2048][1024] bf16
    const float* __restrict__ bih, const float* __restrict__ bhh,
    float* __restrict__ hnext, float* __restrict__ cst,
    float* __restrict__ dout)                // d_out + t*B*H
{
  extern __shared__ char smem[];
  unsigned short (*As)[LDP] = (unsigned short(*)[LDP])smem;                    // [64][LDP]
  unsigned short (*Bs)[LDP] = (unsigned short(*)[LDP])(smem + 64 * LDP * 2);   // [128][LDP]
  float (*Gs)[128] = (float(*)[128])smem;  // aliases staging; used after final barrier

  const int tid = threadIdx.x, wave = tid >> 6, lane = tid & 63;
  const int b0 = blockIdx.y * 64;
  const int j0 = blockIdx.x * 32;

  f32x4 acc[4][2];
#pragma unroll
  for (int i = 0; i < 4; i++)
#pragma unroll
    for (int j = 0; j < 2; j++) acc[i][j] = (f32x4){0.f, 0.f, 0.f, 0.f};

  for (int kk = 0; kk < 1024; kk += BK) {
    // A: 64 batch rows x 32 k; k<512 -> x_t (fp32), else h_prev (fp32)
#pragma unroll
    for (int i = 0; i < 2; i++) {
      int slot = tid * 2 + i;
      int row = slot >> 3, c4 = slot & 7;
      int kg = kk + c4 * 4;
      const float* src = (kg < 512) ? (xt + (long)(b0 + row) * 512 + kg)
                                    : (hprev + (long)(b0 + row) * 512 + (kg - 512));
      float4 v = *(const float4*)src;
      *(ushort4*)&As[row][c4 * 4] =
          make_ushort4(f2bf(v.x), f2bf(v.y), f2bf(v.z), f2bf(v.w));
    }
    // B: 128 rows (4 gates x 32 n) x 32 k, already bf16 -> raw 16B copies
#pragma unroll
    for (int i = 0; i < 2; i++) {
      int slot = tid * 2 + i;            // row = slot>>2 (0..127), c8 = slot&3
      int row = slot >> 2, c8 = slot & 3;
      int g = row >> 5, nn = row & 31;
      const unsigned short* src = Wcat + (long)(g * 512 + j0 + nn) * 1024 + kk + c8 * 8;
      *(uint4*)&Bs[row][c8 * 8] = *(const uint4*)src;
    }
    __syncthreads();

    const int kf = (lane >> 4) * 8;
    const int rl = lane & 15;
    bf16x8 bfr0 = *(const bf16x8*)&Bs[wave * 32 + rl][kf];
    bf16x8 bfr1 = *(const bf16x8*)&Bs[wave * 32 + 16 + rl][kf];
#pragma unroll
    for (int mt = 0; mt < 4; mt++) {
      bf16x8 a = *(const bf16x8*)&As[mt * 16 + rl][kf];
      acc[mt][0] = __builtin_amdgcn_mfma_f32_16x16x32_bf16(a, bfr0, acc[mt][0], 0, 0, 0);
      acc[mt][1] = __builtin_amdgcn_mfma_f32_16x16x32_bf16(a, bfr1, acc[mt][1], 0, 0, 0);
    }
    __syncthreads();   // also protects Gs aliasing below
  }

  // gates -> LDS  (Gs[row][gate*32 + j'])
  const int rq = (lane >> 4) * 4;
  const int cl = lane & 15;
#pragma unroll
  for (int mt = 0; mt < 4; mt++)
#pragma unroll
    for (int nt = 0; nt < 2; nt++) {
      int jj = nt * 16 + cl;
#pragma unroll
      for (int r = 0; r < 4; r++)
        Gs[mt * 16 + rq + r][wave * 32 + jj] = acc[mt][nt][r];
    }
  __syncthreads();

  // cell update: thread -> row=tid>>2 (0..63), 8 consecutive j'
  int row = tid >> 2;
  int jb = (tid & 3) * 8;
  int b = b0 + row;
#pragma unroll
  for (int q = 0; q < 8; q++) {
    int jp = jb + q;
    int j = j0 + jp;
    float gi = Gs[row][jp]      + bih[j]        + bhh[j];
    float gf = Gs[row][32 + jp] + bih[512 + j]  + bhh[512 + j];
    float gg = Gs[row][64 + jp] + bih[1024 + j] + bhh[1024 + j];
    float go = Gs[row][96 + jp] + bih[1536 + j] + bhh[1536 + j];
    float ii = 1.f / (1.f + __expf(-gi));
    float ff = 1.f / (1.f + __expf(-gf));
    float g2 = tanhf(gg);
    float oo = 1.f / (1.f + __expf(-go));
    long idx = (long)b * 512 + j;
    float c = ff * cst[idx] + ii * g2;
    float hv = oo * tanhf(c);
    cst[idx] = c;
    hnext[idx] = hv;
    dout[idx] = hv;
  }
}

extern "C" void kernel_launch(void* const* d_in, const int* in_sizes, int n_in,
                              void* d_out, int out_size, void* d_ws, size_t ws_size,
                              hipStream_t stream) {
  const float* h     = (const float*)d_in[0];
  const float* enc   = (const float*)d_in[1];
  const float* Wattn = (const float*)d_in[2];
  const float* battn = (const float*)d_in[3];
  const float* Wcomb = (const float*)d_in[4];
  const float* bcomb = (const float*)d_in[5];
  const float* Wih   = (const float*)d_in[6];
  const float* Whh   = (const float*)d_in[7];
  const float* bih   = (const float*)d_in[8];
  const float* bhh   = (const float*)d_in[9];
  float* out = (float*)d_out;

  // workspace carve (~70 MB total)
  char* w = (char*)d_ws;
  float* Pbuf = (float*)w;                   w += (size_t)64 * BB * SS * 4;  // 33.5 MB
  float* AAbuf = (float*)w;                  w += (size_t)64 * BB * SS * 4;  // 33.5 MB
  unsigned short* Wcat = (unsigned short*)w; w += (size_t)2048 * 1024 * 2;   // 4 MB
  float* hbuf = (float*)w;                   w += (size_t)2 * BB * HH * 4;   // ping-pong h
  float* cbuf = (float*)w;                   w += (size_t)BB * HH * 4;

  hipMemsetAsync(hbuf, 0, (size_t)BB * HH * 4, stream);  // h0 = 0
  hipMemsetAsync(cbuf, 0, (size_t)BB * HH * 4, stream);  // c0 = 0
  prep_wcat<<<8192, 256, 0, stream>>>(Wih, Whh, Wcat);

  // ---- attention, s-chunked by 64 ----
  const int CH = 64;
  for (int c = 0; c < SS / CH; c++) {
    long roff = (long)c * CH * BB;           // row offset into flattened [S*B]
    const float* hC = h + roff * HH;
    const float* eC = enc + roff * HH;
    // K1: P = [h|enc] @ Wattn^T + battn   (M=16384, N=512, K=1024, NT)
    gemm_bf16<<<dim3(512 / BN, CH * BB / BM, 1), 256, 0, stream>>>(
        hC, eC, Wattn, battn, Pbuf, 1024, 512,
        512, 512, 1024, 512, 0, 0, 0, 0);
    // softmax rows
    softmax512<<<CH * BB / 4, 256, 0, stream>>>(Pbuf);
    // K3: AA_b = P_b @ enc_b  (M=64, N=512, K=512, z=b, NN)
    gemm_bf16<<<dim3(512 / BN, CH / BM, BB), 256, 0, stream>>>(
        Pbuf, Pbuf, enc, nullptr, AAbuf, 512, 1 << 30,
        (long)BB * SS, (long)BB * SS, (long)BB * HH, (long)BB * HH,
        (long)SS, (long)HH, (long)HH, 1);
    // K4: attended = [h|AA] @ Wcomb^T + bcomb -> d_out second half
    gemm_bf16<<<dim3(512 / BN, CH * BB / BM, 1), 256, 0, stream>>>(
        hC, AAbuf, Wcomb, bcomb, out + (size_t)SS * BB * HH + roff * HH,
        1024, 512, 512, 512, 1024, 512, 0, 0, 0, 0);
  }

  // ---- LSTM scan: 512 sequential steps ----
  for (int t = 0; t < SS; t++) {
    lstm_step<<<dim3(16, 4), 256, 32768, stream>>>(
        h + (long)t * BB * HH, hbuf + (size_t)(t & 1) * BB * HH, Wcat, bih, bhh,
        hbuf + (size_t)((t + 1) & 1) * BB * HH, cbuf, out + (long)t * BB * HH);
  }
}